// Round 1
// baseline (1868.503 us; speedup 1.0000x reference)
//
#include <hip/hip_runtime.h>

#define N_NODES 50000
#define NE 1000000

// ws layout (floats):
//   AX  [N*64]  @ 0
//   AE  [N*16]  @ 3,200,000
//   CNT [N]     @ 4,000,000
//   AH  [N*64]  @ 4,050,000
//   H   [N*64]  @ 7,250,000
// memset covers [0, 7,250,000) floats = 29 MB each launch.

__global__ __launch_bounds__(256) void scatter1(
    const float* __restrict__ x, const int* __restrict__ ei,
    const float* __restrict__ ea, float* __restrict__ AX,
    float* __restrict__ AE, float* __restrict__ CNT) {
  int tid = blockIdx.x * 256 + threadIdx.x;
  int e = tid >> 4;
  int l = tid & 15;
  if (e >= NE) return;
  int src = ei[e];
  int dst = ei[NE + e];
  float4 xv = ((const float4*)x)[src * 16 + l];
  float* axp = AX + dst * 64 + l * 4;
  atomicAdd(axp + 0, xv.x);
  atomicAdd(axp + 1, xv.y);
  atomicAdd(axp + 2, xv.z);
  atomicAdd(axp + 3, xv.w);
  float ev = ea[e * 16 + l];
  atomicAdd(AE + dst * 16 + l, ev);
  if (l == 0) atomicAdd(CNT + dst, 1.0f);
}

__global__ __launch_bounds__(256) void scatter2(
    const float* __restrict__ H, const int* __restrict__ ei,
    float* __restrict__ AH) {
  int tid = blockIdx.x * 256 + threadIdx.x;
  int e = tid >> 4;
  int l = tid & 15;
  if (e >= NE) return;
  int src = ei[e];
  int dst = ei[NE + e];
  float4 hv = ((const float4*)H)[src * 16 + l];
  float* ahp = AH + dst * 64 + l * 4;
  atomicAdd(ahp + 0, hv.x);
  atomicAdd(ahp + 1, hv.y);
  atomicAdd(ahp + 2, hv.z);
  atomicAdd(ahp + 3, hv.w);
}

// out[i][j] = relu( sum_k x[i][k]*Ws[k][j] + bs[j] + bn[j]
//                   + ((AGG[i]+x[i])@Wn_top + AE[i]@Wn_bot)[j] / (CNT[i]+1) )
// Implemented as M[i][0:144] = [x | (AGG+x)*inv | AE*inv],
//               Wc[0:144]    = [Ws ; Wn(all 80 rows)]
__global__ __launch_bounds__(256) void layer_kernel(
    const float* __restrict__ xin,   // [N,64]
    const float* __restrict__ AGG,   // [N,64]
    const float* __restrict__ AE,    // [N,16]
    const float* __restrict__ CNT,   // [N]
    const float* __restrict__ Ws,    // [64,64]
    const float* __restrict__ bs,    // [64]
    const float* __restrict__ Wn,    // [80,64]
    const float* __restrict__ bn,    // [64]
    float* __restrict__ out)         // [N,64]
{
  __shared__ float Ml[144][68];   // transposed M tile: Ml[k][row], pad 68 for b128 align
  __shared__ float Wl[72][64];    // K-chunked weight tile
  __shared__ float biasl[64];
  __shared__ float invl[64];

  int t = threadIdx.x;
  int base = blockIdx.x * 64;

  if (t < 64) {
    int i = base + t;
    invl[t] = (i < N_NODES) ? 1.0f / (CNT[i] + 1.0f) : 0.0f;
    biasl[t] = bs[t] + bn[t];
  }
  __syncthreads();

  // stage M (transposed): part1 x, part2 (AGG+x)*inv, part3 AE*inv
  for (int idx = t; idx < 4096; idx += 256) {
    int r = idx >> 6, k = idx & 63;
    int i = base + r;
    Ml[k][r] = (i < N_NODES) ? xin[i * 64 + k] : 0.0f;
  }
  for (int idx = t; idx < 4096; idx += 256) {
    int r = idx >> 6, k = idx & 63;
    int i = base + r;
    Ml[64 + k][r] = (i < N_NODES) ? (AGG[i * 64 + k] + xin[i * 64 + k]) * invl[r] : 0.0f;
  }
  for (int idx = t; idx < 1024; idx += 256) {
    int r = idx >> 4, k = idx & 15;
    int i = base + r;
    Ml[128 + k][r] = (i < N_NODES) ? AE[i * 16 + k] * invl[r] : 0.0f;
  }

  int tx = t & 15;   // col quarter: cols 4tx..4tx+3
  int ty = t >> 4;   // row quarter: rows 4ty..4ty+3
  float acc[4][4] = {{0.f}};

  for (int kc = 0; kc < 2; ++kc) {
    // stage W chunk rows kc*72 .. kc*72+71
    for (int idx = t; idx < 72 * 64; idx += 256) {
      int lr = idx >> 6, c = idx & 63;
      int k = kc * 72 + lr;
      Wl[lr][c] = (k < 64) ? Ws[k * 64 + c] : Wn[(k - 64) * 64 + c];
    }
    __syncthreads();
    #pragma unroll 8
    for (int k = 0; k < 72; ++k) {
      float4 a = *(const float4*)&Ml[kc * 72 + k][ty * 4];
      float4 b = *(const float4*)&Wl[k][tx * 4];
      float av[4] = {a.x, a.y, a.z, a.w};
      float bv[4] = {b.x, b.y, b.z, b.w};
      #pragma unroll
      for (int ri = 0; ri < 4; ++ri)
        #pragma unroll
        for (int ci = 0; ci < 4; ++ci)
          acc[ri][ci] = fmaf(av[ri], bv[ci], acc[ri][ci]);
    }
    __syncthreads();
  }

  #pragma unroll
  for (int ri = 0; ri < 4; ++ri) {
    int i = base + ty * 4 + ri;
    if (i < N_NODES) {
      float4 o;
      o.x = fmaxf(acc[ri][0] + biasl[tx * 4 + 0], 0.0f);
      o.y = fmaxf(acc[ri][1] + biasl[tx * 4 + 1], 0.0f);
      o.z = fmaxf(acc[ri][2] + biasl[tx * 4 + 2], 0.0f);
      o.w = fmaxf(acc[ri][3] + biasl[tx * 4 + 3], 0.0f);
      ((float4*)out)[i * 16 + tx] = o;
    }
  }
}

extern "C" void kernel_launch(void* const* d_in, const int* in_sizes, int n_in,
                              void* d_out, int out_size, void* d_ws, size_t ws_size,
                              hipStream_t stream) {
  const float* x   = (const float*)d_in[0];
  const int*   ei  = (const int*)d_in[1];
  const float* ea  = (const float*)d_in[2];
  const float* W1n = (const float*)d_in[3];
  const float* b1n = (const float*)d_in[4];
  const float* W1s = (const float*)d_in[5];
  const float* b1s = (const float*)d_in[6];
  const float* W2n = (const float*)d_in[7];
  const float* b2n = (const float*)d_in[8];
  const float* W2s = (const float*)d_in[9];
  const float* b2s = (const float*)d_in[10];

  float* wsf = (float*)d_ws;
  float* AX  = wsf;
  float* AE  = wsf + 3200000;
  float* CNT = wsf + 4000000;
  float* AH  = wsf + 4050000;
  float* H   = wsf + 7250000;
  float* out = (float*)d_out;

  hipMemsetAsync(d_ws, 0, 29000000, stream);

  scatter1<<<62500, 256, 0, stream>>>(x, ei, ea, AX, AE, CNT);
  layer_kernel<<<782, 256, 0, stream>>>(x, AX, AE, CNT, W1s, b1s, W1n, b1n, H);
  scatter2<<<62500, 256, 0, stream>>>(H, ei, AH);
  layer_kernel<<<782, 256, 0, stream>>>(H, AH, AE, CNT, W2s, b2s, W2n, b2n, out);
}

// Round 3
// 424.347 us; speedup vs baseline: 4.4032x; 4.4032x over previous
//
#include <hip/hip_runtime.h>

#define N_NODES 50000
#define NE 1000000

// ws layout (4-byte units), total 6,050,004 floats = 24.2 MB (< 29 MB proven safe):
//   OFF  [N+1]    @ 0
//   SRT  [E int2] @ 50004      (byte 200016, 8B aligned)
//   AX   [N*64]f  @ 2050004    (byte 8200016, 16B aligned)
//     HIST [N] aliases @ 2050004, CUR [N] aliases @ 2100004 (dead after sort;
//     gather_agg fully overwrites AX)
//   AE   [N*16]f  @ 5250004    (byte 21000016, 16B aligned)
// H buffer eliminated: layer1 writes d_out, layer2 runs in-place on d_out.

__global__ __launch_bounds__(256) void hist_kernel(
    const int* __restrict__ ei, int* __restrict__ HIST) {
  int e = blockIdx.x * 256 + threadIdx.x;
  if (e >= NE) return;
  atomicAdd(&HIST[ei[NE + e]], 1);
}

// single block, 1024 threads, each owns 49 consecutive bins
__global__ __launch_bounds__(1024) void scan_kernel(
    const int* __restrict__ HIST, int* __restrict__ OFF, int* __restrict__ CUR) {
  __shared__ int sdata[1024];
  int t = threadIdx.x;
  int base = t * 49;
  int sum = 0;
  for (int j = 0; j < 49; ++j) {
    int idx = base + j;
    if (idx < N_NODES) sum += HIST[idx];
  }
  sdata[t] = sum;
  __syncthreads();
  for (int off = 1; off < 1024; off <<= 1) {
    int v = (t >= off) ? sdata[t - off] : 0;
    __syncthreads();
    sdata[t] += v;
    __syncthreads();
  }
  int run = (t > 0) ? sdata[t - 1] : 0;
  for (int j = 0; j < 49; ++j) {
    int idx = base + j;
    if (idx < N_NODES) {
      OFF[idx] = run;
      CUR[idx] = run;
      run += HIST[idx];
    }
  }
  if (t == 1023) OFF[N_NODES] = sdata[1023];
}

__global__ __launch_bounds__(256) void sort_kernel(
    const int* __restrict__ ei, int* __restrict__ CUR, int2* __restrict__ SRT) {
  int e = blockIdx.x * 256 + threadIdx.x;
  if (e >= NE) return;
  int src = ei[e];
  int dst = ei[NE + e];
  int p = atomicAdd(&CUR[dst], 1);
  SRT[p] = make_int2(src, e);
}

// one wave per node: lanes 0..63 = 4 edge-slots x 16 feature-quads
template <bool HAS_EA>
__global__ __launch_bounds__(256) void gather_agg(
    const float* __restrict__ feat,  // [N,64]
    const float* __restrict__ ea,    // [E,16] or null
    const int2* __restrict__ SRT, const int* __restrict__ OFF,
    float* __restrict__ AGG,         // [N,64]
    float* __restrict__ AEout)       // [N,16] or null
{
  int w = (blockIdx.x * 256 + threadIdx.x) >> 6;
  int lane = threadIdx.x & 63;
  if (w >= N_NODES) return;
  int s = OFF[w], e_end = OFF[w + 1];
  int sub = lane >> 4;   // edge slot 0..3
  int q = lane & 15;     // feature quad 0..15
  float4 acc = make_float4(0.f, 0.f, 0.f, 0.f);
  float acce = 0.f;
  for (int p = s + sub; p < e_end; p += 4) {
    int2 se = SRT[p];
    float4 v = ((const float4*)feat)[se.x * 16 + q];
    acc.x += v.x; acc.y += v.y; acc.z += v.z; acc.w += v.w;
    if (HAS_EA) acce += ea[se.y * 16 + q];
  }
  #pragma unroll
  for (int off = 16; off <= 32; off <<= 1) {
    acc.x += __shfl_xor(acc.x, off, 64);
    acc.y += __shfl_xor(acc.y, off, 64);
    acc.z += __shfl_xor(acc.z, off, 64);
    acc.w += __shfl_xor(acc.w, off, 64);
    if (HAS_EA) acce += __shfl_xor(acce, off, 64);
  }
  if (lane < 16) {
    ((float4*)AGG)[w * 16 + q] = acc;
    if (HAS_EA) AEout[w * 16 + q] = acce;
  }
}

// out[i][:] = relu( x@Ws + bs + bn + ((AGG+x)@Wn_top + AE@Wn_bot)/(deg+1) )
// Safe to run in-place (out == xin): each block stages its own 64 rows into
// LDS before writing exactly those rows.
__global__ __launch_bounds__(256) void layer_kernel(
    const float* __restrict__ xin,   // [N,64]
    const float* __restrict__ AGG,   // [N,64]
    const float* __restrict__ AE,    // [N,16]
    const int* __restrict__ OFF,     // [N+1]
    const float* __restrict__ Ws,    // [64,64]
    const float* __restrict__ bs,    // [64]
    const float* __restrict__ Wn,    // [80,64]
    const float* __restrict__ bn,    // [64]
    float* __restrict__ out)         // [N,64]
{
  __shared__ float Ml[144][68];
  __shared__ float Wl[72][64];
  __shared__ float biasl[64];
  __shared__ float invl[64];

  int t = threadIdx.x;
  int base = blockIdx.x * 64;

  if (t < 64) {
    int i = base + t;
    float deg = (i < N_NODES) ? (float)(OFF[i + 1] - OFF[i]) : 0.0f;
    invl[t] = 1.0f / (deg + 1.0f);
    biasl[t] = bs[t] + bn[t];
  }
  __syncthreads();

  for (int idx = t; idx < 4096; idx += 256) {
    int r = idx >> 6, k = idx & 63;
    int i = base + r;
    Ml[k][r] = (i < N_NODES) ? xin[i * 64 + k] : 0.0f;
  }
  for (int idx = t; idx < 4096; idx += 256) {
    int r = idx >> 6, k = idx & 63;
    int i = base + r;
    Ml[64 + k][r] = (i < N_NODES) ? (AGG[i * 64 + k] + xin[i * 64 + k]) * invl[r] : 0.0f;
  }
  for (int idx = t; idx < 1024; idx += 256) {
    int r = idx >> 4, k = idx & 15;
    int i = base + r;
    Ml[128 + k][r] = (i < N_NODES) ? AE[i * 16 + k] * invl[r] : 0.0f;
  }

  int tx = t & 15;
  int ty = t >> 4;
  float acc[4][4] = {{0.f}};

  for (int kc = 0; kc < 2; ++kc) {
    for (int idx = t; idx < 72 * 64; idx += 256) {
      int lr = idx >> 6, c = idx & 63;
      int k = kc * 72 + lr;
      Wl[lr][c] = (k < 64) ? Ws[k * 64 + c] : Wn[(k - 64) * 64 + c];
    }
    __syncthreads();
    #pragma unroll 8
    for (int k = 0; k < 72; ++k) {
      float4 a = *(const float4*)&Ml[kc * 72 + k][ty * 4];
      float4 b = *(const float4*)&Wl[k][tx * 4];
      float av[4] = {a.x, a.y, a.z, a.w};
      float bv[4] = {b.x, b.y, b.z, b.w};
      #pragma unroll
      for (int ri = 0; ri < 4; ++ri)
        #pragma unroll
        for (int ci = 0; ci < 4; ++ci)
          acc[ri][ci] = fmaf(av[ri], bv[ci], acc[ri][ci]);
    }
    __syncthreads();
  }

  #pragma unroll
  for (int ri = 0; ri < 4; ++ri) {
    int i = base + ty * 4 + ri;
    if (i < N_NODES) {
      float4 o;
      o.x = fmaxf(acc[ri][0] + biasl[tx * 4 + 0], 0.0f);
      o.y = fmaxf(acc[ri][1] + biasl[tx * 4 + 1], 0.0f);
      o.z = fmaxf(acc[ri][2] + biasl[tx * 4 + 2], 0.0f);
      o.w = fmaxf(acc[ri][3] + biasl[tx * 4 + 3], 0.0f);
      ((float4*)out)[i * 16 + tx] = o;
    }
  }
}

extern "C" void kernel_launch(void* const* d_in, const int* in_sizes, int n_in,
                              void* d_out, int out_size, void* d_ws, size_t ws_size,
                              hipStream_t stream) {
  const float* x   = (const float*)d_in[0];
  const int*   ei  = (const int*)d_in[1];
  const float* ea  = (const float*)d_in[2];
  const float* W1n = (const float*)d_in[3];
  const float* b1n = (const float*)d_in[4];
  const float* W1s = (const float*)d_in[5];
  const float* b1s = (const float*)d_in[6];
  const float* W2n = (const float*)d_in[7];
  const float* b2n = (const float*)d_in[8];
  const float* W2s = (const float*)d_in[9];
  const float* b2s = (const float*)d_in[10];

  int* wsi = (int*)d_ws;
  float* wsf = (float*)d_ws;
  int*  OFF  = wsi;                       // [0, 50001)
  int2* SRT  = (int2*)(wsi + 50004);      // [50004, 2050004)
  float* AX  = wsf + 2050004;             // [2050004, 5250004)
  int*  HIST = wsi + 2050004;             // aliases AX (dead after sort)
  int*  CUR  = wsi + 2100004;             // aliases AX (dead after sort)
  float* AE  = wsf + 5250004;             // [5250004, 6050004)
  float* out = (float*)d_out;

  hipMemsetAsync(HIST, 0, N_NODES * 4, stream);

  int eb = (NE + 255) / 256;
  hist_kernel<<<eb, 256, 0, stream>>>(ei, HIST);
  scan_kernel<<<1, 1024, 0, stream>>>(HIST, OFF, CUR);
  sort_kernel<<<eb, 256, 0, stream>>>(ei, CUR, SRT);

  int ab = (N_NODES * 64 + 255) / 256;  // 12500 blocks, 1 wave/node
  gather_agg<true><<<ab, 256, 0, stream>>>(x, ea, SRT, OFF, AX, AE);
  layer_kernel<<<782, 256, 0, stream>>>(x, AX, AE, OFF, W1s, b1s, W1n, b1n, out);
  gather_agg<false><<<ab, 256, 0, stream>>>(out, nullptr, SRT, OFF, AX, nullptr);
  layer_kernel<<<782, 256, 0, stream>>>(out, AX, AE, OFF, W2s, b2s, W2n, b2n, out);
}

// Round 5
// 307.008 us; speedup vs baseline: 6.0862x; 1.3822x over previous
//
#include <hip/hip_runtime.h>

#define N_NODES 50000
#define NE 1000000
#define NBLK 196  // ceil(50000/256)

// ws layout (4-byte units), total ~6,050,260 ints/floats = 24.2 MB (< 29 MB proven safe):
//   OFF  [N+1]    @ 0
//   SRT  [E int2] @ 50004      (byte 200016, 8B aligned)
//   AX   [N*64]f  @ 2050004    (byte 8200016, 16B aligned)
//     HIST [N] aliases @ 2050004, CUR [N] aliases @ 2100004 (dead after sort;
//     gather_agg fully overwrites AX)
//   AE   [N*16]f  @ 5250004
//   BSUM [256]    @ 6050004
// Layer1 writes d_out; layer2 runs in-place on d_out.

__global__ __launch_bounds__(256) void hist_kernel(
    const int* __restrict__ ei, int* __restrict__ HIST) {
  int e = blockIdx.x * 256 + threadIdx.x;
  if (e >= NE) return;
  atomicAdd(&HIST[ei[NE + e]], 1);
}

// stage 1: per-block coalesced exclusive scan of 256 bins -> OFF, block sum -> BSUM
__global__ __launch_bounds__(256) void scan_local(
    const int* __restrict__ HIST, int* __restrict__ OFF, int* __restrict__ BSUM) {
  __shared__ int s[256];
  int t = threadIdx.x;
  int g = blockIdx.x * 256 + t;
  int v = (g < N_NODES) ? HIST[g] : 0;
  s[t] = v;
  __syncthreads();
  #pragma unroll
  for (int off = 1; off < 256; off <<= 1) {
    int u = (t >= off) ? s[t - off] : 0;
    __syncthreads();
    s[t] += u;
    __syncthreads();
  }
  if (t == 255) BSUM[blockIdx.x] = s[255];
  if (g < N_NODES) OFF[g] = s[t] - v;  // exclusive within block
}

// stage 2: single block scans the 196 block sums in place (exclusive), total -> OFF[N]
__global__ __launch_bounds__(256) void scan_bsums(
    int* __restrict__ BSUM, int* __restrict__ OFF) {
  __shared__ int s[256];
  int t = threadIdx.x;
  int v = (t < NBLK) ? BSUM[t] : 0;
  s[t] = v;
  __syncthreads();
  #pragma unroll
  for (int off = 1; off < 256; off <<= 1) {
    int u = (t >= off) ? s[t - off] : 0;
    __syncthreads();
    s[t] += u;
    __syncthreads();
  }
  if (t < NBLK) BSUM[t] = s[t] - v;  // exclusive block offset
  if (t == 255) OFF[N_NODES] = s[255];
}

// stage 3: add block offsets, mirror into CUR
__global__ __launch_bounds__(256) void scan_add(
    int* __restrict__ OFF, const int* __restrict__ BSUM, int* __restrict__ CUR) {
  int g = blockIdx.x * 256 + threadIdx.x;
  if (g >= N_NODES) return;
  int o = OFF[g] + BSUM[blockIdx.x];
  OFF[g] = o;
  CUR[g] = o;
}

__global__ __launch_bounds__(256) void sort_kernel(
    const int* __restrict__ ei, int* __restrict__ CUR, int2* __restrict__ SRT) {
  int e = blockIdx.x * 256 + threadIdx.x;
  if (e >= NE) return;
  int src = ei[e];
  int dst = ei[NE + e];
  int p = atomicAdd(&CUR[dst], 1);
  SRT[p] = make_int2(src, e);
}

// one wave per node: lanes 0..63 = 4 edge-slots x 16 feature-quads
template <bool HAS_EA>
__global__ __launch_bounds__(256) void gather_agg(
    const float* __restrict__ feat,  // [N,64]
    const float* __restrict__ ea,    // [E,16] or null
    const int2* __restrict__ SRT, const int* __restrict__ OFF,
    float* __restrict__ AGG,         // [N,64]
    float* __restrict__ AEout)       // [N,16] or null
{
  int w = (blockIdx.x * 256 + threadIdx.x) >> 6;
  int lane = threadIdx.x & 63;
  if (w >= N_NODES) return;
  int s = OFF[w], e_end = OFF[w + 1];
  int sub = lane >> 4;   // edge slot 0..3
  int q = lane & 15;     // feature quad 0..15
  float4 acc = make_float4(0.f, 0.f, 0.f, 0.f);
  float acce = 0.f;
  for (int p = s + sub; p < e_end; p += 4) {
    int2 se = SRT[p];
    float4 v = ((const float4*)feat)[se.x * 16 + q];
    acc.x += v.x; acc.y += v.y; acc.z += v.z; acc.w += v.w;
    if (HAS_EA) acce += ea[se.y * 16 + q];
  }
  #pragma unroll
  for (int off = 16; off <= 32; off <<= 1) {
    acc.x += __shfl_xor(acc.x, off, 64);
    acc.y += __shfl_xor(acc.y, off, 64);
    acc.z += __shfl_xor(acc.z, off, 64);
    acc.w += __shfl_xor(acc.w, off, 64);
    if (HAS_EA) acce += __shfl_xor(acce, off, 64);
  }
  if (lane < 16) {
    ((float4*)AGG)[w * 16 + q] = acc;
    if (HAS_EA) AEout[w * 16 + q] = acce;
  }
}

// out[i][:] = relu( x@Ws + bs + bn + ((AGG+x)@Wn_top + AE@Wn_bot)/(deg+1) )
// Safe in-place (out == xin): block stages its 64 rows in LDS before writing them.
__global__ __launch_bounds__(256) void layer_kernel(
    const float* __restrict__ xin,   // [N,64]
    const float* __restrict__ AGG,   // [N,64]
    const float* __restrict__ AE,    // [N,16]
    const int* __restrict__ OFF,     // [N+1]
    const float* __restrict__ Ws,    // [64,64]
    const float* __restrict__ bs,    // [64]
    const float* __restrict__ Wn,    // [80,64]
    const float* __restrict__ bn,    // [64]
    float* __restrict__ out)         // [N,64]
{
  __shared__ float Ml[144][68];
  __shared__ float Wl[72][64];
  __shared__ float biasl[64];
  __shared__ float invl[64];

  int t = threadIdx.x;
  int base = blockIdx.x * 64;

  if (t < 64) {
    int i = base + t;
    float deg = (i < N_NODES) ? (float)(OFF[i + 1] - OFF[i]) : 0.0f;
    invl[t] = 1.0f / (deg + 1.0f);
    biasl[t] = bs[t] + bn[t];
  }
  __syncthreads();

  for (int idx = t; idx < 4096; idx += 256) {
    int r = idx >> 6, k = idx & 63;
    int i = base + r;
    Ml[k][r] = (i < N_NODES) ? xin[i * 64 + k] : 0.0f;
  }
  for (int idx = t; idx < 4096; idx += 256) {
    int r = idx >> 6, k = idx & 63;
    int i = base + r;
    Ml[64 + k][r] = (i < N_NODES) ? (AGG[i * 64 + k] + xin[i * 64 + k]) * invl[r] : 0.0f;
  }
  for (int idx = t; idx < 1024; idx += 256) {
    int r = idx >> 4, k = idx & 15;
    int i = base + r;
    Ml[128 + k][r] = (i < N_NODES) ? AE[i * 16 + k] * invl[r] : 0.0f;
  }

  int tx = t & 15;
  int ty = t >> 4;
  float acc[4][4] = {{0.f}};

  for (int kc = 0; kc < 2; ++kc) {
    for (int idx = t; idx < 72 * 64; idx += 256) {
      int lr = idx >> 6, c = idx & 63;
      int k = kc * 72 + lr;
      Wl[lr][c] = (k < 64) ? Ws[k * 64 + c] : Wn[(k - 64) * 64 + c];
    }
    __syncthreads();
    #pragma unroll 8
    for (int k = 0; k < 72; ++k) {
      float4 a = *(const float4*)&Ml[kc * 72 + k][ty * 4];
      float4 b = *(const float4*)&Wl[k][tx * 4];
      float av[4] = {a.x, a.y, a.z, a.w};
      float bv[4] = {b.x, b.y, b.z, b.w};
      #pragma unroll
      for (int ri = 0; ri < 4; ++ri)
        #pragma unroll
        for (int ci = 0; ci < 4; ++ci)
          acc[ri][ci] = fmaf(av[ri], bv[ci], acc[ri][ci]);
    }
    __syncthreads();
  }

  #pragma unroll
  for (int ri = 0; ri < 4; ++ri) {
    int i = base + ty * 4 + ri;
    if (i < N_NODES) {
      float4 o;
      o.x = fmaxf(acc[ri][0] + biasl[tx * 4 + 0], 0.0f);
      o.y = fmaxf(acc[ri][1] + biasl[tx * 4 + 1], 0.0f);
      o.z = fmaxf(acc[ri][2] + biasl[tx * 4 + 2], 0.0f);
      o.w = fmaxf(acc[ri][3] + biasl[tx * 4 + 3], 0.0f);
      ((float4*)out)[i * 16 + tx] = o;
    }
  }
}

extern "C" void kernel_launch(void* const* d_in, const int* in_sizes, int n_in,
                              void* d_out, int out_size, void* d_ws, size_t ws_size,
                              hipStream_t stream) {
  const float* x   = (const float*)d_in[0];
  const int*   ei  = (const int*)d_in[1];
  const float* ea  = (const float*)d_in[2];
  const float* W1n = (const float*)d_in[3];
  const float* b1n = (const float*)d_in[4];
  const float* W1s = (const float*)d_in[5];
  const float* b1s = (const float*)d_in[6];
  const float* W2n = (const float*)d_in[7];
  const float* b2n = (const float*)d_in[8];
  const float* W2s = (const float*)d_in[9];
  const float* b2s = (const float*)d_in[10];

  int* wsi = (int*)d_ws;
  float* wsf = (float*)d_ws;
  int*  OFF  = wsi;                       // [0, 50001)
  int2* SRT  = (int2*)(wsi + 50004);      // [50004, 2050004)
  float* AX  = wsf + 2050004;             // [2050004, 5250004)
  int*  HIST = wsi + 2050004;             // aliases AX (dead after sort)
  int*  CUR  = wsi + 2100004;             // aliases AX (dead after sort)
  float* AE  = wsf + 5250004;             // [5250004, 6050004)
  int*  BSUM = wsi + 6050004;             // [6050004, 6050260)
  float* out = (float*)d_out;

  hipMemsetAsync(HIST, 0, N_NODES * 4, stream);

  int eb = (NE + 255) / 256;
  hist_kernel<<<eb, 256, 0, stream>>>(ei, HIST);
  scan_local<<<NBLK, 256, 0, stream>>>(HIST, OFF, BSUM);
  scan_bsums<<<1, 256, 0, stream>>>(BSUM, OFF);
  scan_add<<<NBLK, 256, 0, stream>>>(OFF, BSUM, CUR);
  sort_kernel<<<eb, 256, 0, stream>>>(ei, CUR, SRT);

  int ab = (N_NODES * 64 + 255) / 256;  // 12500 blocks, 1 wave/node
  gather_agg<true><<<ab, 256, 0, stream>>>(x, ea, SRT, OFF, AX, AE);
  layer_kernel<<<782, 256, 0, stream>>>(x, AX, AE, OFF, W1s, b1s, W1n, b1n, out);
  gather_agg<false><<<ab, 256, 0, stream>>>(out, nullptr, SRT, OFF, AX, nullptr);
  layer_kernel<<<782, 256, 0, stream>>>(out, AX, AE, OFF, W2s, b2s, W2n, b2n, out);
}